// Round 5
// baseline (1011.111 us; speedup 1.0000x reference)
//
#include <hip/hip_runtime.h>

// GAE forward on MI355X.
// Pipeline: cast -> t1T=W1T@featT -> h1=relu(adj@t1+b1) [split-K] ->
//           t2T=W2T@h1T -> h=adj@t2+b2 [split-K] -> out=sigmoid(h@hT), h.
// All MFMA GEMMs use the "bt" convention: X[M,K], Y[N,K] row-major, C = X*Y^T.
// Frag layout (m89-verified): A/B lane = X[l16][k+q*8..+8] (16B load);
// C/D: col = lane&15, row = q*4 + reg.
//
// R8: adj GEMM rewritten BARRIER-FREE (gemm_adj_direct). The old LDS-staged
// version drained vmcnt(0) at a __syncthreads every 64-wide K-tile (32
// drains/block, 2 barrier-groups/CU) — the classic structural stall. New
// design: each wave loads the 64x64 fp32 A-tile directly to registers
// (16 rows x 128B full lines per frag pair; NT policy keeps the L2-resident
// B panels safe; 4-wave same-line reads dedup in L1/MSHR since NT is
// evict-priority, not bypass). Two-stage named-register prefetch, no LDS,
// zero barriers. Everything else identical to R7.

typedef __bf16 bf16x8_t __attribute__((ext_vector_type(8)));
typedef __bf16 bf16x4_t __attribute__((ext_vector_type(4)));
typedef float  f32x4_t  __attribute__((ext_vector_type(4)));

#define MFMA_BF16(a, b, c) __builtin_amdgcn_mfma_f32_16x16x32_bf16((a), (b), (c), 0, 0, 0)

__device__ __forceinline__ bf16x8_t cvt8(f32x4_t u, f32x4_t v) {
    bf16x8_t o;
    o[0] = (__bf16)u[0]; o[1] = (__bf16)u[1]; o[2] = (__bf16)u[2]; o[3] = (__bf16)u[3];
    o[4] = (__bf16)v[0]; o[5] = (__bf16)v[1]; o[6] = (__bf16)v[2]; o[7] = (__bf16)v[3];
    return o;
}

__device__ __forceinline__ f32x4_t nt_load4(const float* p) {
    return __builtin_nontemporal_load((const f32x4_t*)p);
}
__device__ __forceinline__ void nt_store4(f32x4_t v, float* p) {
    __builtin_nontemporal_store(v, (f32x4_t*)p);
}

// ---- cast feature -> bf16 (8 elems/thread), W1 -> W1T bf16, W2 -> W2T bf16 ----
__global__ __launch_bounds__(256) void cast_all(
    const float* __restrict__ feat, const float* __restrict__ W1,
    const float* __restrict__ W2, __bf16* __restrict__ fb,
    __bf16* __restrict__ w1t, __bf16* __restrict__ w2t)
{
    const int j = blockIdx.x * 256 + threadIdx.x;
    if (j < 524288) {                     // feature: 8192*512 / 8
        const float* p = feat + (size_t)j * 8;
        f32x4_t u = nt_load4(p);
        f32x4_t v = nt_load4(p + 4);
        *(bf16x8_t*)(fb + (size_t)j * 8) = cvt8(u, v);
    } else if (j < 524288 + 131072) {     // W1 [512][256] -> W1T [256][512]
        int t = j - 524288;
        int k = t >> 8, n = t & 255;
        w1t[n * 512 + k] = (__bf16)W1[t];
    } else if (j < 524288 + 131072 + 32768) { // W2 [256][128] -> W2T [128][256]
        int t = j - 655360;
        int k = t >> 7, n = t & 127;
        w2t[n * 256 + k] = (__bf16)W2[t];
    }
}

// ---- small bf16 GEMM, C (bf16) = X * Y^T ----
template<int MT, int WC>
__global__ __launch_bounds__(256, 2) void gemm_bt_cbf16(
    const __bf16* __restrict__ X, const __bf16* __restrict__ Yb,
    __bf16* __restrict__ C, int K, int N)
{
    constexpr int WR = 4 / WC;
    constexpr int BM = WR * MT * 16;
    constexpr int BN = WC * 64;
    const int mblk = blockIdx.x, nblk = blockIdx.y;
    const int w = threadIdx.x >> 6, lane = threadIdx.x & 63;
    const int wr = w / WC, wc = w % WC;
    const int q = lane >> 4, l16 = lane & 15;
    const int mbase = mblk * BM + wr * (MT * 16);
    const int nbase = nblk * BN + wc * 64;

    f32x4_t acc[MT][4];
    const f32x4_t z = {0.f, 0.f, 0.f, 0.f};
#pragma unroll
    for (int i = 0; i < MT; i++)
#pragma unroll
        for (int jj = 0; jj < 4; jj++) acc[i][jj] = z;

    const __bf16* Xr[MT];
    const __bf16* Yr[4];
#pragma unroll
    for (int i = 0; i < MT; i++) Xr[i] = X + (size_t)(mbase + i * 16 + l16) * K + q * 8;
#pragma unroll
    for (int jj = 0; jj < 4; jj++) Yr[jj] = Yb + (size_t)(nbase + jj * 16 + l16) * K + q * 8;

    for (int k = 0; k < K; k += 32) {
        bf16x8_t a[MT], b[4];
#pragma unroll
        for (int i = 0; i < MT; i++) a[i] = *(const bf16x8_t*)(Xr[i] + k);
#pragma unroll
        for (int jj = 0; jj < 4; jj++) b[jj] = *(const bf16x8_t*)(Yr[jj] + k);
#pragma unroll
        for (int i = 0; i < MT; i++)
#pragma unroll
            for (int jj = 0; jj < 4; jj++) acc[i][jj] = MFMA_BF16(a[i], b[jj], acc[i][jj]);
    }

#pragma unroll
    for (int i = 0; i < MT; i++)
#pragma unroll
        for (int jj = 0; jj < 4; jj++) {
            const int row0 = mbase + i * 16 + q * 4;
            const int col = nbase + jj * 16 + l16;
#pragma unroll
            for (int r = 0; r < 4; r++)
                C[(size_t)(row0 + r) * N + col] = (__bf16)acc[i][jj][r];
        }
}

// ---- adj GEMM, barrier-free: each wave loads the 64-row fp32 A-tile
// directly to registers. Lane(l16,q) of frag i reads row mblk*64+i*16+l16,
// cols k+q*8..+8 (two f32x4, 16 lines x 128B per frag pair — fully used).
// NT on A: evict-priority keeps 4-wave short-window L1 dedup while not
// polluting L2 (B panels t1T/t2T stay resident). Two-stage named-register
// prefetch (k+32 in flight over compute on k). Wave-grid 1x4 over columns.
template<int NN>
__global__ __launch_bounds__(256, 2) void gemm_adj_direct(
    const float* __restrict__ A, const __bf16* __restrict__ Y,
    float* __restrict__ P, int kchunk)
{
    constexpr int NT = NN / 64;          // n-tiles per wave (1x4 wave grid)
    const int mblk = blockIdx.x;
    const int ks = blockIdx.y;
    const int w = threadIdx.x >> 6, lane = threadIdx.x & 63;
    const int q = lane >> 4, l16 = lane & 15;
    const int kbase = ks * kchunk;

    const float* Ar[4];
#pragma unroll
    for (int i = 0; i < 4; i++)
        Ar[i] = A + (size_t)(mblk * 64 + i * 16 + l16) * 8192 + kbase + q * 8;

    const __bf16* Yr[NT];
#pragma unroll
    for (int jj = 0; jj < NT; jj++)
        Yr[jj] = Y + (size_t)(w * (NN / 4) + jj * 16 + l16) * 8192 + kbase + q * 8;

    f32x4_t acc[4][NT];
    const f32x4_t z = {0.f, 0.f, 0.f, 0.f};
#pragma unroll
    for (int i = 0; i < 4; i++)
#pragma unroll
        for (int jj = 0; jj < NT; jj++) acc[i][jj] = z;

    // stage A (k): ua/va ; stage B (k): bfa ; stage A (k+32): ub/vb ; B: bfb
    f32x4_t ua[4], va[4], ub[4], vb[4];
    bf16x8_t bfa[NT], bfb[NT];

    // preload k=0
#pragma unroll
    for (int i = 0; i < 4; i++) {
        ua[i] = nt_load4(Ar[i]);
        va[i] = nt_load4(Ar[i] + 4);
    }
#pragma unroll
    for (int jj = 0; jj < NT; jj++) bfa[jj] = *(const bf16x8_t*)(Yr[jj]);

    for (int k = 0; k < kchunk; k += 64) {
        // prefetch k+32
#pragma unroll
        for (int i = 0; i < 4; i++) {
            ub[i] = nt_load4(Ar[i] + k + 32);
            vb[i] = nt_load4(Ar[i] + k + 36);
        }
#pragma unroll
        for (int jj = 0; jj < NT; jj++)
            bfb[jj] = *(const bf16x8_t*)(Yr[jj] + k + 32);

        // compute k
        {
            bf16x8_t afr[4];
#pragma unroll
            for (int i = 0; i < 4; i++) afr[i] = cvt8(ua[i], va[i]);
#pragma unroll
            for (int i = 0; i < 4; i++)
#pragma unroll
                for (int jj = 0; jj < NT; jj++)
                    acc[i][jj] = MFMA_BF16(afr[i], bfa[jj], acc[i][jj]);
        }

        // prefetch k+64 (next iteration's first half)
        if (k + 64 < kchunk) {
#pragma unroll
            for (int i = 0; i < 4; i++) {
                ua[i] = nt_load4(Ar[i] + k + 64);
                va[i] = nt_load4(Ar[i] + k + 68);
            }
#pragma unroll
            for (int jj = 0; jj < NT; jj++)
                bfa[jj] = *(const bf16x8_t*)(Yr[jj] + k + 64);
        }

        // compute k+32
        {
            bf16x8_t afr[4];
#pragma unroll
            for (int i = 0; i < 4; i++) afr[i] = cvt8(ub[i], vb[i]);
#pragma unroll
            for (int i = 0; i < 4; i++)
#pragma unroll
                for (int jj = 0; jj < NT; jj++)
                    acc[i][jj] = MFMA_BF16(afr[i], bfb[jj], acc[i][jj]);
        }
    }

    // NT partial stores: r-outer/jj-inner so consecutive stores form 256B
    // runs within one row (write-merge friendly).
#pragma unroll
    for (int i = 0; i < 4; i++) {
        const int row0 = mblk * 64 + i * 16 + q * 4;
#pragma unroll
        for (int r = 0; r < 4; r++) {
            float* pp = P + ((size_t)ks * 8192 + row0 + r) * NN + w * (NN / 4) + l16;
#pragma unroll
            for (int jj = 0; jj < NT; jj++)
                __builtin_nontemporal_store(acc[i][jj][r], pp + jj * 16);
        }
    }
}

// ---- epilogue 1: h1 = relu(sum_ks partial + b1) -> bf16 [8192][256] ----
__global__ __launch_bounds__(256) void epi_relu_bias(
    const float* __restrict__ P, const float* __restrict__ bias,
    __bf16* __restrict__ H)
{
    const size_t SL = (size_t)8192 * 256;
    const size_t idx = ((size_t)blockIdx.x * 256 + threadIdx.x) * 4;
    f32x4_t s0 = nt_load4(P + idx);
    f32x4_t s1 = nt_load4(P + SL + idx);
    f32x4_t s2 = nt_load4(P + 2 * SL + idx);
    f32x4_t s3 = nt_load4(P + 3 * SL + idx);
    const int col = (int)(idx & 255);
    f32x4_t bb = *(const f32x4_t*)(bias + col);
    bf16x4_t o;
#pragma unroll
    for (int e = 0; e < 4; e++)
        o[e] = (__bf16)fmaxf(s0[e] + s1[e] + s2[e] + s3[e] + bb[e], 0.f);
    *(bf16x4_t*)(H + idx) = o;   // cacheable: re-read by t2T GEMM
}

// ---- epilogue 2: h = sum_ks partial + b2 -> fp32 d_out tail AND bf16 copy ----
__global__ __launch_bounds__(256) void epi_bias_out(
    const float* __restrict__ P, const float* __restrict__ bias,
    float* __restrict__ Hout, __bf16* __restrict__ Hbf)
{
    const size_t SL = (size_t)8192 * 128;
    const size_t idx = ((size_t)blockIdx.x * 256 + threadIdx.x) * 4;
    f32x4_t s0 = nt_load4(P + idx);
    f32x4_t s1 = nt_load4(P + SL + idx);
    f32x4_t s2 = nt_load4(P + 2 * SL + idx);
    f32x4_t s3 = nt_load4(P + 3 * SL + idx);
    const int col = (int)(idx & 127);
    f32x4_t bb = *(const f32x4_t*)(bias + col);
    f32x4_t o;
#pragma unroll
    for (int e = 0; e < 4; e++)
        o[e] = s0[e] + s1[e] + s2[e] + s3[e] + bb[e];
    nt_store4(o, Hout + idx);   // write-once tail of d_out
    bf16x4_t ob;
#pragma unroll
    for (int e = 0; e < 4; e++) ob[e] = (__bf16)o[e];
    *(bf16x4_t*)(Hbf + idx) = ob;   // cacheable: re-read 128x by gemm_sig
}

// ---- decoder: out[r][s] = sigmoid(h[r,:].h[s,:]), K=128 unrolled.
// Epilogue: sigmoid in-reg -> LDS tile (two 64-row half-passes, 132-float
// padded rows) -> coalesced dwordx4 NT stores. 4 blocks/CU. ----
__global__ __launch_bounds__(256, 4) void gemm_sig(
    const __bf16* __restrict__ H, float* __restrict__ out)
{
    __shared__ float S[64 * 132];        // 33792 B

    const int mblk = blockIdx.x, nblk = blockIdx.y;
    const int w = threadIdx.x >> 6, lane = threadIdx.x & 63;
    const int wr = w >> 1, wc = w & 1;
    const int q = lane >> 4, l16 = lane & 15;
    const int mbase = mblk * 128 + wr * 64;
    const int nbase = nblk * 128 + wc * 64;

    f32x4_t acc[4][4];
    const f32x4_t z = {0.f, 0.f, 0.f, 0.f};
#pragma unroll
    for (int i = 0; i < 4; i++)
#pragma unroll
        for (int jj = 0; jj < 4; jj++) acc[i][jj] = z;

#pragma unroll
    for (int k = 0; k < 128; k += 32) {
        bf16x8_t a[4], b[4];
#pragma unroll
        for (int i = 0; i < 4; i++)
            a[i] = *(const bf16x8_t*)(H + (size_t)(mbase + i * 16 + l16) * 128 + k + q * 8);
#pragma unroll
        for (int jj = 0; jj < 4; jj++)
            b[jj] = *(const bf16x8_t*)(H + (size_t)(nbase + jj * 16 + l16) * 128 + k + q * 8);
#pragma unroll
        for (int i = 0; i < 4; i++)
#pragma unroll
            for (int jj = 0; jj < 4; jj++) acc[i][jj] = MFMA_BF16(a[i], b[jj], acc[i][jj]);
    }

    // Two half-passes: half h covers fragment rows ii = h*2 + {0,1} of every
    // wave, i.e. global rows mblk*128 + wr*64 + h*32 + (0..31).
#pragma unroll
    for (int h = 0; h < 2; h++) {
        if (h) __syncthreads();          // drain(h=0) done before overwrite
#pragma unroll
        for (int i = 0; i < 2; i++) {
            const int ii = h * 2 + i;
            const int lrow = wr * 32 + i * 16 + q * 4;   // LDS row (0..63)
#pragma unroll
            for (int jj = 0; jj < 4; jj++) {
                const int col = wc * 64 + jj * 16 + l16;
#pragma unroll
                for (int r = 0; r < 4; r++) {
                    const float x = acc[ii][jj][r];
                    S[(lrow + r) * 132 + col] = 1.0f / (1.0f + __expf(-x));
                }
            }
        }
        __syncthreads();
        // drain 64 rows x 128 cols = 2048 dwordx4, fully coalesced
#pragma unroll
        for (int it = 0; it < 8; it++) {
            const int gid = it * 256 + (int)threadIdx.x;
            const int lr = gid >> 5;             // 0..63
            const int qd = gid & 31;             // 16B quad
            f32x4_t v = *(const f32x4_t*)(S + lr * 132 + qd * 4);
            const int grow = mblk * 128 + (lr >> 5) * 64 + (lr & 31) + h * 32;
            const int gcol = nblk * 128 + qd * 4;
            nt_store4(v, out + (size_t)grow * 8192 + gcol);
        }
    }
}

extern "C" void kernel_launch(void* const* d_in, const int* in_sizes, int n_in,
                              void* d_out, int out_size, void* d_ws, size_t ws_size,
                              hipStream_t stream)
{
    const float* adj  = (const float*)d_in[0];
    const float* feat = (const float*)d_in[1];
    const float* W1   = (const float*)d_in[2];
    const float* b1   = (const float*)d_in[3];
    const float* W2   = (const float*)d_in[4];
    const float* b2   = (const float*)d_in[5];
    float* out = (float*)d_out;

    // workspace layout (~52.3 MB total)
    char* p = (char*)d_ws;
    __bf16* featbf = (__bf16*)p; p += (size_t)8192 * 512 * 2;  // 8 MB
    __bf16* W1T    = (__bf16*)p; p += (size_t)256 * 512 * 2;   // 256 KB
    __bf16* W2T    = (__bf16*)p; p += (size_t)128 * 256 * 2;   // 64 KB
    __bf16* t1T    = (__bf16*)p; p += (size_t)256 * 8192 * 2;  // 4 MB
    __bf16* h1     = (__bf16*)p; p += (size_t)8192 * 256 * 2;  // 4 MB
    __bf16* t2T    = (__bf16*)p; p += (size_t)128 * 8192 * 2;  // 2 MB
    __bf16* hbf    = (__bf16*)p; p += (size_t)8192 * 128 * 2;  // 2 MB
    float* part    = (float*)p;                                 // 32 MB (reused 16 MB)

    // 1. casts
    cast_all<<<2688, 256, 0, stream>>>(feat, W1, W2, featbf, W1T, W2T);
    // 2. t1T[256][8192] = W1T * feat^T
    gemm_bt_cbf16<2, 2><<<dim3(4, 64), 256, 0, stream>>>(W1T, featbf, t1T, 512, 8192);
    // 3. partials of adj @ t1  (split-K=4, barrier-free direct-load)
    gemm_adj_direct<256><<<dim3(128, 4), 256, 0, stream>>>(adj, t1T, part, 2048);
    // 4. h1 = relu(sum + b1) -> bf16
    epi_relu_bias<<<2048, 256, 0, stream>>>(part, b1, h1);
    // 5. t2T[128][8192] = W2T * h1^T
    gemm_bt_cbf16<2, 2><<<dim3(2, 64), 256, 0, stream>>>(W2T, h1, t2T, 256, 8192);
    // 6. partials of adj @ t2  (split-K=4, barrier-free direct-load)
    gemm_adj_direct<128><<<dim3(128, 4), 256, 0, stream>>>(adj, t2T, part, 2048);
    // 7. h = sum + b2 -> fp32 out tail + bf16 copy
    epi_bias_out<<<1024, 256, 0, stream>>>(part, b2, out + (size_t)8192 * 8192, hbf);
    // 8. out = sigmoid(h @ h^T)
    gemm_sig<<<dim3(64, 64), 256, 0, stream>>>(hbf, out);
}

// Round 6
// 652.772 us; speedup vs baseline: 1.5490x; 1.5490x over previous
//
#include <hip/hip_runtime.h>

// GAE forward on MI355X.
// Pipeline: cast -> t1T=W1T@featT -> h1=relu(adj@t1+b1) [split-K] ->
//           t2T=W2T@h1T -> h=adj@t2+b2 [split-K] -> out=sigmoid(h@hT), h.
// All MFMA GEMMs use the "bt" convention: X[M,K], Y[N,K] row-major, C = X*Y^T.
// Frag layout (m89-verified): A/B lane = X[l16][k+q*8..+8] (16B load);
// C/D: col = lane&15, row = q*4 + reg.
//
// R9: revert R8's latency-bound direct-load adj (300us/dispatch @18% HBM,
// occupancy-starved register pipeline) back to LDS-DMA staging, and widen
// the K-tile BK 64 -> 128 (64x128 fp32 tile, 32KB x2 dbuf = 64KB LDS,
// 2 blocks/CU): halves the __syncthreads vmcnt(0) drains (32 -> 16 per
// block) and doubles the compute window per drain (~500 -> ~1000cy, >= DMA
// latency). R8 data backs out adj_lds = ~114us each vs ~55us floor; the
// drain cadence is the identified gap. Swizzle generalized: 32 granules,
// XOR (row&31) — same bank-quad distribution mod 8 as the proven BK=64.

typedef __bf16 bf16x8_t __attribute__((ext_vector_type(8)));
typedef __bf16 bf16x4_t __attribute__((ext_vector_type(4)));
typedef float  f32x4_t  __attribute__((ext_vector_type(4)));

#define MFMA_BF16(a, b, c) __builtin_amdgcn_mfma_f32_16x16x32_bf16((a), (b), (c), 0, 0, 0)

__device__ __forceinline__ bf16x8_t cvt8(f32x4_t u, f32x4_t v) {
    bf16x8_t o;
    o[0] = (__bf16)u[0]; o[1] = (__bf16)u[1]; o[2] = (__bf16)u[2]; o[3] = (__bf16)u[3];
    o[4] = (__bf16)v[0]; o[5] = (__bf16)v[1]; o[6] = (__bf16)v[2]; o[7] = (__bf16)v[3];
    return o;
}

__device__ __forceinline__ f32x4_t nt_load4(const float* p) {
    return __builtin_nontemporal_load((const f32x4_t*)p);
}
__device__ __forceinline__ void nt_store4(f32x4_t v, float* p) {
    __builtin_nontemporal_store(v, (f32x4_t*)p);
}

// width-16 global->LDS DMA; AUX=2 sets the non-temporal cache policy
template<int AUX>
__device__ __forceinline__ void gload_lds16(const float* g, float* l) {
    __builtin_amdgcn_global_load_lds(
        (const __attribute__((address_space(1))) unsigned int*)g,
        (__attribute__((address_space(3))) unsigned int*)l, 16, 0, AUX);
}

// ---- cast feature -> bf16 (8 elems/thread), W1 -> W1T bf16, W2 -> W2T bf16 ----
__global__ __launch_bounds__(256) void cast_all(
    const float* __restrict__ feat, const float* __restrict__ W1,
    const float* __restrict__ W2, __bf16* __restrict__ fb,
    __bf16* __restrict__ w1t, __bf16* __restrict__ w2t)
{
    const int j = blockIdx.x * 256 + threadIdx.x;
    if (j < 524288) {                     // feature: 8192*512 / 8
        const float* p = feat + (size_t)j * 8;
        f32x4_t u = nt_load4(p);
        f32x4_t v = nt_load4(p + 4);
        *(bf16x8_t*)(fb + (size_t)j * 8) = cvt8(u, v);
    } else if (j < 524288 + 131072) {     // W1 [512][256] -> W1T [256][512]
        int t = j - 524288;
        int k = t >> 8, n = t & 255;
        w1t[n * 512 + k] = (__bf16)W1[t];
    } else if (j < 524288 + 131072 + 32768) { // W2 [256][128] -> W2T [128][256]
        int t = j - 655360;
        int k = t >> 7, n = t & 127;
        w2t[n * 256 + k] = (__bf16)W2[t];
    }
}

// ---- small bf16 GEMM, C (bf16) = X * Y^T ----
template<int MT, int WC>
__global__ __launch_bounds__(256, 2) void gemm_bt_cbf16(
    const __bf16* __restrict__ X, const __bf16* __restrict__ Yb,
    __bf16* __restrict__ C, int K, int N)
{
    constexpr int WR = 4 / WC;
    constexpr int BM = WR * MT * 16;
    constexpr int BN = WC * 64;
    const int mblk = blockIdx.x, nblk = blockIdx.y;
    const int w = threadIdx.x >> 6, lane = threadIdx.x & 63;
    const int wr = w / WC, wc = w % WC;
    const int q = lane >> 4, l16 = lane & 15;
    const int mbase = mblk * BM + wr * (MT * 16);
    const int nbase = nblk * BN + wc * 64;

    f32x4_t acc[MT][4];
    const f32x4_t z = {0.f, 0.f, 0.f, 0.f};
#pragma unroll
    for (int i = 0; i < MT; i++)
#pragma unroll
        for (int jj = 0; jj < 4; jj++) acc[i][jj] = z;

    const __bf16* Xr[MT];
    const __bf16* Yr[4];
#pragma unroll
    for (int i = 0; i < MT; i++) Xr[i] = X + (size_t)(mbase + i * 16 + l16) * K + q * 8;
#pragma unroll
    for (int jj = 0; jj < 4; jj++) Yr[jj] = Yb + (size_t)(nbase + jj * 16 + l16) * K + q * 8;

    for (int k = 0; k < K; k += 32) {
        bf16x8_t a[MT], b[4];
#pragma unroll
        for (int i = 0; i < MT; i++) a[i] = *(const bf16x8_t*)(Xr[i] + k);
#pragma unroll
        for (int jj = 0; jj < 4; jj++) b[jj] = *(const bf16x8_t*)(Yr[jj] + k);
#pragma unroll
        for (int i = 0; i < MT; i++)
#pragma unroll
            for (int jj = 0; jj < 4; jj++) acc[i][jj] = MFMA_BF16(a[i], b[jj], acc[i][jj]);
    }

#pragma unroll
    for (int i = 0; i < MT; i++)
#pragma unroll
        for (int jj = 0; jj < 4; jj++) {
            const int row0 = mbase + i * 16 + q * 4;
            const int col = nbase + jj * 16 + l16;
#pragma unroll
            for (int r = 0; r < 4; r++)
                C[(size_t)(row0 + r) * N + col] = (__bf16)acc[i][jj][r];
        }
}

// ---- adj GEMM: fp32 A staged via NT global_load_lds into double-buffered LDS.
// BK=128: tile = 64 rows x 128 cols fp32 (32KB), 2 buffers = 64KB LDS,
// 2 blocks/CU. 16 barrier-drains per block (was 32 at BK=64), compute window
// per drain ~2x DMA latency. Source-column XOR swizzle @16B granules:
// LDS granule g at row r holds global granule (g ^ (r&31)) — read side XORs
// identically; bank-quad distribution (mod 8) matches the proven BK=64 map.
// Wave-grid 1x4 over columns: wave computes all 64 rows x NN/4 cols.
// B frags for all 4 K-substeps issued BEFORE the barrier (L2 hits complete
// during the drain). ----
template<int NN>
__global__ __launch_bounds__(256, 2) void gemm_adj_lds(
    const float* __restrict__ A, const __bf16* __restrict__ Y,
    float* __restrict__ P, int kchunk)
{
    constexpr int NT = NN / 64;          // n-tiles per wave (1x4 wave grid)
    __shared__ float As[2][8192];        // 2 x 64 rows x 128 cols fp32 = 64KB

    const int mblk = blockIdx.x;
    const int ks = blockIdx.y;
    const int w = threadIdx.x >> 6, lane = threadIdx.x & 63;
    const int q = lane >> 4, l16 = lane & 15;
    const int kbase = ks * kchunk;
    const int ntiles = kchunk >> 7;      // BK=128

    // staging: instr j (j=0..7) covers rows j*8 + w*2 + (lane>>5), granule
    // lane&31. LDS dst = uniform base + lane*16 (DMA constraint); global
    // source granule = (lg ^ (row&31)) so LDS granule lg holds swizzled data.
    const int lr = lane >> 5;            // 0..1
    const int lg = lane & 31;            // granule 0..31 (16B each)
    const float* gsrc[8];
    int loff[8];
#pragma unroll
    for (int j = 0; j < 8; j++) {
        const int row = j * 8 + w * 2 + lr;
        const int colswz = ((lg ^ (row & 31)) << 2);
        gsrc[j] = A + (size_t)(mblk * 64 + row) * 8192 + kbase + colswz;
        loff[j] = row * 128 + (lg << 2);
    }

    const __bf16* Yr[NT];
#pragma unroll
    for (int jj = 0; jj < NT; jj++)
        Yr[jj] = Y + (size_t)(w * (NN / 4) + jj * 16 + l16) * 8192 + q * 8;

    f32x4_t acc[4][NT];
    const f32x4_t z = {0.f, 0.f, 0.f, 0.f};
#pragma unroll
    for (int i = 0; i < 4; i++)
#pragma unroll
        for (int jj = 0; jj < NT; jj++) acc[i][jj] = z;

    // preload tile 0 (NT cpol: don't pollute L2 with streaming adj)
#pragma unroll
    for (int j = 0; j < 8; j++) gload_lds16<2>(gsrc[j], &As[0][0] + loff[j]);

    int buf = 0;
    for (int kt = 0; kt < ntiles; kt++) {
        const int kk = kbase + (kt << 7);

        // B fragments for this K-tile (4 substeps), issued BEFORE the
        // barrier: L2-hits that complete during the barrier's DMA drain.
        bf16x8_t breg[4][NT];
#pragma unroll
        for (int s = 0; s < 4; s++)
#pragma unroll
            for (int jj = 0; jj < NT; jj++)
                breg[s][jj] = *(const bf16x8_t*)(Yr[jj] + kk + s * 32);

        __syncthreads();   // tile kt DMA complete; prev compute done

        if (kt + 1 < ntiles) {
            const int koff = (kt + 1) << 7;
#pragma unroll
            for (int j = 0; j < 8; j++)
                gload_lds16<2>(gsrc[j] + koff, &As[buf ^ 1][0] + loff[j]);
        }

        const float* __restrict__ L = &As[buf][0];
#pragma unroll
        for (int s = 0; s < 4; s++) {
            bf16x8_t a[4];
#pragma unroll
            for (int i = 0; i < 4; i++) {
                const int r = i * 16 + l16;              // tile-local row
                const int g0 = ((s * 8 + q * 2) ^ (r & 31)) << 2;
                const int g1 = ((s * 8 + q * 2 + 1) ^ (r & 31)) << 2;
                f32x4_t u = *(const f32x4_t*)(L + r * 128 + g0);
                f32x4_t v = *(const f32x4_t*)(L + r * 128 + g1);
                a[i] = cvt8(u, v);
            }
#pragma unroll
            for (int i = 0; i < 4; i++)
#pragma unroll
                for (int jj = 0; jj < NT; jj++)
                    acc[i][jj] = MFMA_BF16(a[i], breg[s][jj], acc[i][jj]);
        }
        buf ^= 1;
    }

    // NT partial stores: r-outer/jj-inner so consecutive stores form 256B
    // runs within one row (write-merge friendly).
#pragma unroll
    for (int i = 0; i < 4; i++) {
        const int row0 = mblk * 64 + i * 16 + q * 4;
#pragma unroll
        for (int r = 0; r < 4; r++) {
            float* pp = P + ((size_t)ks * 8192 + row0 + r) * NN + w * (NN / 4) + l16;
#pragma unroll
            for (int jj = 0; jj < NT; jj++)
                __builtin_nontemporal_store(acc[i][jj][r], pp + jj * 16);
        }
    }
}

// ---- epilogue 1: h1 = relu(sum_ks partial + b1) -> bf16 [8192][256] ----
__global__ __launch_bounds__(256) void epi_relu_bias(
    const float* __restrict__ P, const float* __restrict__ bias,
    __bf16* __restrict__ H)
{
    const size_t SL = (size_t)8192 * 256;
    const size_t idx = ((size_t)blockIdx.x * 256 + threadIdx.x) * 4;
    f32x4_t s0 = nt_load4(P + idx);
    f32x4_t s1 = nt_load4(P + SL + idx);
    f32x4_t s2 = nt_load4(P + 2 * SL + idx);
    f32x4_t s3 = nt_load4(P + 3 * SL + idx);
    const int col = (int)(idx & 255);
    f32x4_t bb = *(const f32x4_t*)(bias + col);
    bf16x4_t o;
#pragma unroll
    for (int e = 0; e < 4; e++)
        o[e] = (__bf16)fmaxf(s0[e] + s1[e] + s2[e] + s3[e] + bb[e], 0.f);
    *(bf16x4_t*)(H + idx) = o;   // cacheable: re-read by t2T GEMM
}

// ---- epilogue 2: h = sum_ks partial + b2 -> fp32 d_out tail AND bf16 copy ----
__global__ __launch_bounds__(256) void epi_bias_out(
    const float* __restrict__ P, const float* __restrict__ bias,
    float* __restrict__ Hout, __bf16* __restrict__ Hbf)
{
    const size_t SL = (size_t)8192 * 128;
    const size_t idx = ((size_t)blockIdx.x * 256 + threadIdx.x) * 4;
    f32x4_t s0 = nt_load4(P + idx);
    f32x4_t s1 = nt_load4(P + SL + idx);
    f32x4_t s2 = nt_load4(P + 2 * SL + idx);
    f32x4_t s3 = nt_load4(P + 3 * SL + idx);
    const int col = (int)(idx & 127);
    f32x4_t bb = *(const f32x4_t*)(bias + col);
    f32x4_t o;
#pragma unroll
    for (int e = 0; e < 4; e++)
        o[e] = s0[e] + s1[e] + s2[e] + s3[e] + bb[e];
    nt_store4(o, Hout + idx);   // write-once tail of d_out
    bf16x4_t ob;
#pragma unroll
    for (int e = 0; e < 4; e++) ob[e] = (__bf16)o[e];
    *(bf16x4_t*)(Hbf + idx) = ob;   // cacheable: re-read 128x by gemm_sig
}

// ---- decoder: out[r][s] = sigmoid(h[r,:].h[s,:]), K=128 unrolled.
// Epilogue: sigmoid in-reg -> LDS tile (two 64-row half-passes, 132-float
// padded rows) -> coalesced dwordx4 NT stores. 4 blocks/CU. ----
__global__ __launch_bounds__(256, 4) void gemm_sig(
    const __bf16* __restrict__ H, float* __restrict__ out)
{
    __shared__ float S[64 * 132];        // 33792 B

    const int mblk = blockIdx.x, nblk = blockIdx.y;
    const int w = threadIdx.x >> 6, lane = threadIdx.x & 63;
    const int wr = w >> 1, wc = w & 1;
    const int q = lane >> 4, l16 = lane & 15;
    const int mbase = mblk * 128 + wr * 64;
    const int nbase = nblk * 128 + wc * 64;

    f32x4_t acc[4][4];
    const f32x4_t z = {0.f, 0.f, 0.f, 0.f};
#pragma unroll
    for (int i = 0; i < 4; i++)
#pragma unroll
        for (int jj = 0; jj < 4; jj++) acc[i][jj] = z;

#pragma unroll
    for (int k = 0; k < 128; k += 32) {
        bf16x8_t a[4], b[4];
#pragma unroll
        for (int i = 0; i < 4; i++)
            a[i] = *(const bf16x8_t*)(H + (size_t)(mbase + i * 16 + l16) * 128 + k + q * 8);
#pragma unroll
        for (int jj = 0; jj < 4; jj++)
            b[jj] = *(const bf16x8_t*)(H + (size_t)(nbase + jj * 16 + l16) * 128 + k + q * 8);
#pragma unroll
        for (int i = 0; i < 4; i++)
#pragma unroll
            for (int jj = 0; jj < 4; jj++) acc[i][jj] = MFMA_BF16(a[i], b[jj], acc[i][jj]);
    }

    // Two half-passes: half h covers fragment rows ii = h*2 + {0,1} of every
    // wave, i.e. global rows mblk*128 + wr*64 + h*32 + (0..31).
#pragma unroll
    for (int h = 0; h < 2; h++) {
        if (h) __syncthreads();          // drain(h=0) done before overwrite
#pragma unroll
        for (int i = 0; i < 2; i++) {
            const int ii = h * 2 + i;
            const int lrow = wr * 32 + i * 16 + q * 4;   // LDS row (0..63)
#pragma unroll
            for (int jj = 0; jj < 4; jj++) {
                const int col = wc * 64 + jj * 16 + l16;
#pragma unroll
                for (int r = 0; r < 4; r++) {
                    const float x = acc[ii][jj][r];
                    S[(lrow + r) * 132 + col] = 1.0f / (1.0f + __expf(-x));
                }
            }
        }
        __syncthreads();
        // drain 64 rows x 128 cols = 2048 dwordx4, fully coalesced
#pragma unroll
        for (int it = 0; it < 8; it++) {
            const int gid = it * 256 + (int)threadIdx.x;
            const int lr = gid >> 5;             // 0..63
            const int qd = gid & 31;             // 16B quad
            f32x4_t v = *(const f32x4_t*)(S + lr * 132 + qd * 4);
            const int grow = mblk * 128 + (lr >> 5) * 64 + (lr & 31) + h * 32;
            const int gcol = nblk * 128 + qd * 4;
            nt_store4(v, out + (size_t)grow * 8192 + gcol);
        }
    }
}

extern "C" void kernel_launch(void* const* d_in, const int* in_sizes, int n_in,
                              void* d_out, int out_size, void* d_ws, size_t ws_size,
                              hipStream_t stream)
{
    const float* adj  = (const float*)d_in[0];
    const float* feat = (const float*)d_in[1];
    const float* W1   = (const float*)d_in[2];
    const float* b1   = (const float*)d_in[3];
    const float* W2   = (const float*)d_in[4];
    const float* b2   = (const float*)d_in[5];
    float* out = (float*)d_out;

    // workspace layout (~52.3 MB total)
    char* p = (char*)d_ws;
    __bf16* featbf = (__bf16*)p; p += (size_t)8192 * 512 * 2;  // 8 MB
    __bf16* W1T    = (__bf16*)p; p += (size_t)256 * 512 * 2;   // 256 KB
    __bf16* W2T    = (__bf16*)p; p += (size_t)128 * 256 * 2;   // 64 KB
    __bf16* t1T    = (__bf16*)p; p += (size_t)256 * 8192 * 2;  // 4 MB
    __bf16* h1     = (__bf16*)p; p += (size_t)8192 * 256 * 2;  // 4 MB
    __bf16* t2T    = (__bf16*)p; p += (size_t)128 * 8192 * 2;  // 2 MB
    __bf16* hbf    = (__bf16*)p; p += (size_t)8192 * 128 * 2;  // 2 MB
    float* part    = (float*)p;                                 // 32 MB (reused 16 MB)

    // 1. casts
    cast_all<<<2688, 256, 0, stream>>>(feat, W1, W2, featbf, W1T, W2T);
    // 2. t1T[256][8192] = W1T * feat^T
    gemm_bt_cbf16<2, 2><<<dim3(4, 64), 256, 0, stream>>>(W1T, featbf, t1T, 512, 8192);
    // 3. partials of adj @ t1  (split-K=4, LDS-staged BK=128)
    gemm_adj_lds<256><<<dim3(128, 4), 256, 0, stream>>>(adj, t1T, part, 2048);
    // 4. h1 = relu(sum + b1) -> bf16
    epi_relu_bias<<<2048, 256, 0, stream>>>(part, b1, h1);
    // 5. t2T[128][8192] = W2T * h1^T
    gemm_bt_cbf16<2, 2><<<dim3(2, 64), 256, 0, stream>>>(W2T, h1, t2T, 256, 8192);
    // 6. partials of adj @ t2  (split-K=4, LDS-staged BK=128)
    gemm_adj_lds<128><<<dim3(128, 4), 256, 0, stream>>>(adj, t2T, part, 2048);
    // 7. h = sum + b2 -> fp32 out tail + bf16 copy
    epi_bias_out<<<1024, 256, 0, stream>>>(part, b2, out + (size_t)8192 * 8192, hbf);
    // 8. out = sigmoid(h @ h^T)
    gemm_sig<<<dim3(64, 64), 256, 0, stream>>>(hbf, out);
}

// Round 7
// 639.494 us; speedup vs baseline: 1.5811x; 1.0208x over previous
//
#include <hip/hip_runtime.h>

// GAE forward on MI355X.
// Pipeline: cast -> t1T=W1T@featT -> h1=relu(adj@t1+b1) [split-K] ->
//           t2T=W2T@h1T -> h=adj@t2+b2 [split-K] -> out=sigmoid(h@hT), h.
// All MFMA GEMMs use the "bt" convention: X[M,K], Y[N,K] row-major, C = X*Y^T.
// Frag layout (m89-verified): A/B lane = X[l16][k+q*8..+8] (16B load);
// C/D: col = lane&15, row = q*4 + reg.
//
// R10: adj GEMM restructured for XCD-L2 B-residency. R8's counters showed
// FETCH=385MB (268 adj + ~117MB B-panel refetch): t1T (4MB) == one XCD L2,
// every block needs the whole panel -> all 8 XCDs thrash. Fix: split-K=2,
// 512-thread blocks (8 waves, 64x128 LDS tile, 1 block/CU, grid=256 = exactly
// 1/CU), with ks = blockIdx.x & 1: round-robin blockIdx->XCD maps each XCD to
// ONE k-slice, so its B working set is 2MB (t1) / 1MB (t2) -> L2-resident.
// Also halves split-K partial traffic (32->16MB each way). Side effect: adj
// dispatches now ~2x longer -> visible in top-5 counters for attribution.

typedef __bf16 bf16x8_t __attribute__((ext_vector_type(8)));
typedef __bf16 bf16x4_t __attribute__((ext_vector_type(4)));
typedef float  f32x4_t  __attribute__((ext_vector_type(4)));

#define MFMA_BF16(a, b, c) __builtin_amdgcn_mfma_f32_16x16x32_bf16((a), (b), (c), 0, 0, 0)

__device__ __forceinline__ bf16x8_t cvt8(f32x4_t u, f32x4_t v) {
    bf16x8_t o;
    o[0] = (__bf16)u[0]; o[1] = (__bf16)u[1]; o[2] = (__bf16)u[2]; o[3] = (__bf16)u[3];
    o[4] = (__bf16)v[0]; o[5] = (__bf16)v[1]; o[6] = (__bf16)v[2]; o[7] = (__bf16)v[3];
    return o;
}

__device__ __forceinline__ f32x4_t nt_load4(const float* p) {
    return __builtin_nontemporal_load((const f32x4_t*)p);
}
__device__ __forceinline__ void nt_store4(f32x4_t v, float* p) {
    __builtin_nontemporal_store(v, (f32x4_t*)p);
}

// width-16 global->LDS DMA; AUX=2 sets the non-temporal cache policy
template<int AUX>
__device__ __forceinline__ void gload_lds16(const float* g, float* l) {
    __builtin_amdgcn_global_load_lds(
        (const __attribute__((address_space(1))) unsigned int*)g,
        (__attribute__((address_space(3))) unsigned int*)l, 16, 0, AUX);
}

// ---- cast feature -> bf16 (8 elems/thread), W1 -> W1T bf16, W2 -> W2T bf16 ----
__global__ __launch_bounds__(256) void cast_all(
    const float* __restrict__ feat, const float* __restrict__ W1,
    const float* __restrict__ W2, __bf16* __restrict__ fb,
    __bf16* __restrict__ w1t, __bf16* __restrict__ w2t)
{
    const int j = blockIdx.x * 256 + threadIdx.x;
    if (j < 524288) {                     // feature: 8192*512 / 8
        const float* p = feat + (size_t)j * 8;
        f32x4_t u = nt_load4(p);
        f32x4_t v = nt_load4(p + 4);
        *(bf16x8_t*)(fb + (size_t)j * 8) = cvt8(u, v);
    } else if (j < 524288 + 131072) {     // W1 [512][256] -> W1T [256][512]
        int t = j - 524288;
        int k = t >> 8, n = t & 255;
        w1t[n * 512 + k] = (__bf16)W1[t];
    } else if (j < 524288 + 131072 + 32768) { // W2 [256][128] -> W2T [128][256]
        int t = j - 655360;
        int k = t >> 7, n = t & 127;
        w2t[n * 256 + k] = (__bf16)W2[t];
    }
}

// ---- small bf16 GEMM, C (bf16) = X * Y^T ----
template<int MT, int WC>
__global__ __launch_bounds__(256, 2) void gemm_bt_cbf16(
    const __bf16* __restrict__ X, const __bf16* __restrict__ Yb,
    __bf16* __restrict__ C, int K, int N)
{
    constexpr int WR = 4 / WC;
    constexpr int BM = WR * MT * 16;
    constexpr int BN = WC * 64;
    const int mblk = blockIdx.x, nblk = blockIdx.y;
    const int w = threadIdx.x >> 6, lane = threadIdx.x & 63;
    const int wr = w / WC, wc = w % WC;
    const int q = lane >> 4, l16 = lane & 15;
    const int mbase = mblk * BM + wr * (MT * 16);
    const int nbase = nblk * BN + wc * 64;

    f32x4_t acc[MT][4];
    const f32x4_t z = {0.f, 0.f, 0.f, 0.f};
#pragma unroll
    for (int i = 0; i < MT; i++)
#pragma unroll
        for (int jj = 0; jj < 4; jj++) acc[i][jj] = z;

    const __bf16* Xr[MT];
    const __bf16* Yr[4];
#pragma unroll
    for (int i = 0; i < MT; i++) Xr[i] = X + (size_t)(mbase + i * 16 + l16) * K + q * 8;
#pragma unroll
    for (int jj = 0; jj < 4; jj++) Yr[jj] = Yb + (size_t)(nbase + jj * 16 + l16) * K + q * 8;

    for (int k = 0; k < K; k += 32) {
        bf16x8_t a[MT], b[4];
#pragma unroll
        for (int i = 0; i < MT; i++) a[i] = *(const bf16x8_t*)(Xr[i] + k);
#pragma unroll
        for (int jj = 0; jj < 4; jj++) b[jj] = *(const bf16x8_t*)(Yr[jj] + k);
#pragma unroll
        for (int i = 0; i < MT; i++)
#pragma unroll
            for (int jj = 0; jj < 4; jj++) acc[i][jj] = MFMA_BF16(a[i], b[jj], acc[i][jj]);
    }

#pragma unroll
    for (int i = 0; i < MT; i++)
#pragma unroll
        for (int jj = 0; jj < 4; jj++) {
            const int row0 = mbase + i * 16 + q * 4;
            const int col = nbase + jj * 16 + l16;
#pragma unroll
            for (int r = 0; r < 4; r++)
                C[(size_t)(row0 + r) * N + col] = (__bf16)acc[i][jj][r];
        }
}

// ---- adj GEMM: split-K=2, 512 threads (8 waves), 64x128 fp32 LDS tile
// (32KB x2 dbuf = 64KB), 1 block/CU, grid 256 = exactly one per CU.
// ks = blockIdx.x & 1 -> with round-robin blockIdx->XCD, each XCD serves one
// k-slice only: B working set 2MB (t1) / 1MB (t2), L2-resident.
// Source-column XOR swizzle @16B granules (granule g at row r holds global
// granule g^(r&31)); read side XORs identically. Wave w covers cols
// w*(NN/8)..+NN/8. B frags for all 4 K-substeps issued BEFORE the barrier. ----
template<int NN>
__global__ __launch_bounds__(512, 2) void gemm_adj_lds(
    const float* __restrict__ A, const __bf16* __restrict__ Y,
    float* __restrict__ P)
{
    constexpr int NT = NN / 128;         // 16-col tiles per wave: 2 (t1) / 1 (t2)
    constexpr int KCH = 4096;            // kchunk (split-K=2)
    constexpr int NTILES = KCH / 128;    // 32
    __shared__ float As[2][8192];        // 2 x 64 rows x 128 cols fp32 = 64KB

    const int id = blockIdx.x;           // 0..255
    const int ks = id & 1;               // XCD-locked K-slice
    const int mblk = id >> 1;            // 0..127
    const int w = threadIdx.x >> 6, lane = threadIdx.x & 63;
    const int q = lane >> 4, l16 = lane & 15;
    const int kbase = ks * KCH;

    // staging: 512 lanes x 16B = 8KB per round; 4 rounds per 32KB tile.
    // round j covers rows j*16 + w*2 + (lane>>5), granule lane&31.
    const int lr = lane >> 5;            // 0..1
    const int lg = lane & 31;            // 16B granule 0..31
    const float* gsrc[4];
    int loff[4];
#pragma unroll
    for (int j = 0; j < 4; j++) {
        const int row = j * 16 + w * 2 + lr;
        const int colswz = ((lg ^ (row & 31)) << 2);
        gsrc[j] = A + (size_t)(mblk * 64 + row) * 8192 + kbase + colswz;
        loff[j] = row * 128 + (lg << 2);
    }

    const __bf16* Yr[NT];
#pragma unroll
    for (int jj = 0; jj < NT; jj++)
        Yr[jj] = Y + (size_t)(w * (NN / 8) + jj * 16 + l16) * 8192 + q * 8;

    f32x4_t acc[4][NT];
    const f32x4_t z = {0.f, 0.f, 0.f, 0.f};
#pragma unroll
    for (int i = 0; i < 4; i++)
#pragma unroll
        for (int jj = 0; jj < NT; jj++) acc[i][jj] = z;

    // preload tile 0 (NT cpol: adj must not evict the L2-resident B slice)
#pragma unroll
    for (int j = 0; j < 4; j++) gload_lds16<2>(gsrc[j], &As[0][0] + loff[j]);

    int buf = 0;
    for (int kt = 0; kt < NTILES; kt++) {
        const int kk = kbase + (kt << 7);

        // B fragments for this tile (4 substeps), issued BEFORE the barrier:
        // L2 hits that complete during the barrier's DMA drain.
        bf16x8_t breg[4][NT];
#pragma unroll
        for (int s = 0; s < 4; s++)
#pragma unroll
            for (int jj = 0; jj < NT; jj++)
                breg[s][jj] = *(const bf16x8_t*)(Yr[jj] + kk + s * 32);

        __syncthreads();   // tile kt DMA complete; prev compute done

        if (kt + 1 < NTILES) {
            const int koff = (kt + 1) << 7;
#pragma unroll
            for (int j = 0; j < 4; j++)
                gload_lds16<2>(gsrc[j] + koff, &As[buf ^ 1][0] + loff[j]);
        }

        const float* __restrict__ L = &As[buf][0];
#pragma unroll
        for (int s = 0; s < 4; s++) {
            bf16x8_t a[4];
#pragma unroll
            for (int i = 0; i < 4; i++) {
                const int r = i * 16 + l16;              // tile-local row
                const int g0 = ((s * 8 + q * 2) ^ (r & 31)) << 2;
                const int g1 = ((s * 8 + q * 2 + 1) ^ (r & 31)) << 2;
                f32x4_t u = *(const f32x4_t*)(L + r * 128 + g0);
                f32x4_t v = *(const f32x4_t*)(L + r * 128 + g1);
                a[i] = cvt8(u, v);
            }
#pragma unroll
            for (int i = 0; i < 4; i++)
#pragma unroll
                for (int jj = 0; jj < NT; jj++)
                    acc[i][jj] = MFMA_BF16(a[i], breg[s][jj], acc[i][jj]);
        }
        buf ^= 1;
    }

    // NT partial stores: r-outer/jj-inner, 64B runs per 16-lane quad.
#pragma unroll
    for (int i = 0; i < 4; i++) {
        const int row0 = mblk * 64 + i * 16 + q * 4;
#pragma unroll
        for (int r = 0; r < 4; r++) {
            float* pp = P + ((size_t)ks * 8192 + row0 + r) * NN + w * (NN / 8) + l16;
#pragma unroll
            for (int jj = 0; jj < NT; jj++)
                __builtin_nontemporal_store(acc[i][jj][r], pp + jj * 16);
        }
    }
}

// ---- epilogue 1: h1 = relu(sum of 2 partials + b1) -> bf16 [8192][256] ----
__global__ __launch_bounds__(256) void epi_relu_bias(
    const float* __restrict__ P, const float* __restrict__ bias,
    __bf16* __restrict__ H)
{
    const size_t SL = (size_t)8192 * 256;
    const size_t idx = ((size_t)blockIdx.x * 256 + threadIdx.x) * 4;
    f32x4_t s0 = nt_load4(P + idx);
    f32x4_t s1 = nt_load4(P + SL + idx);
    const int col = (int)(idx & 255);
    f32x4_t bb = *(const f32x4_t*)(bias + col);
    bf16x4_t o;
#pragma unroll
    for (int e = 0; e < 4; e++)
        o[e] = (__bf16)fmaxf(s0[e] + s1[e] + bb[e], 0.f);
    *(bf16x4_t*)(H + idx) = o;   // cacheable: re-read by t2T GEMM
}

// ---- epilogue 2: h = sum of 2 partials + b2 -> fp32 d_out tail AND bf16 copy ----
__global__ __launch_bounds__(256) void epi_bias_out(
    const float* __restrict__ P, const float* __restrict__ bias,
    float* __restrict__ Hout, __bf16* __restrict__ Hbf)
{
    const size_t SL = (size_t)8192 * 128;
    const size_t idx = ((size_t)blockIdx.x * 256 + threadIdx.x) * 4;
    f32x4_t s0 = nt_load4(P + idx);
    f32x4_t s1 = nt_load4(P + SL + idx);
    const int col = (int)(idx & 127);
    f32x4_t bb = *(const f32x4_t*)(bias + col);
    f32x4_t o;
#pragma unroll
    for (int e = 0; e < 4; e++)
        o[e] = s0[e] + s1[e] + bb[e];
    nt_store4(o, Hout + idx);   // write-once tail of d_out
    bf16x4_t ob;
#pragma unroll
    for (int e = 0; e < 4; e++) ob[e] = (__bf16)o[e];
    *(bf16x4_t*)(Hbf + idx) = ob;   // cacheable: re-read by gemm_sig
}

// ---- decoder: out[r][s] = sigmoid(h[r,:].h[s,:]), K=128 unrolled.
// Epilogue: sigmoid in-reg -> LDS tile (two 64-row half-passes, 132-float
// padded rows) -> coalesced dwordx4 NT stores. 4 blocks/CU. ----
__global__ __launch_bounds__(256, 4) void gemm_sig(
    const __bf16* __restrict__ H, float* __restrict__ out)
{
    __shared__ float S[64 * 132];        // 33792 B

    const int mblk = blockIdx.x, nblk = blockIdx.y;
    const int w = threadIdx.x >> 6, lane = threadIdx.x & 63;
    const int wr = w >> 1, wc = w & 1;
    const int q = lane >> 4, l16 = lane & 15;
    const int mbase = mblk * 128 + wr * 64;
    const int nbase = nblk * 128 + wc * 64;

    f32x4_t acc[4][4];
    const f32x4_t z = {0.f, 0.f, 0.f, 0.f};
#pragma unroll
    for (int i = 0; i < 4; i++)
#pragma unroll
        for (int jj = 0; jj < 4; jj++) acc[i][jj] = z;

#pragma unroll
    for (int k = 0; k < 128; k += 32) {
        bf16x8_t a[4], b[4];
#pragma unroll
        for (int i = 0; i < 4; i++)
            a[i] = *(const bf16x8_t*)(H + (size_t)(mbase + i * 16 + l16) * 128 + k + q * 8);
#pragma unroll
        for (int jj = 0; jj < 4; jj++)
            b[jj] = *(const bf16x8_t*)(H + (size_t)(nbase + jj * 16 + l16) * 128 + k + q * 8);
#pragma unroll
        for (int i = 0; i < 4; i++)
#pragma unroll
            for (int jj = 0; jj < 4; jj++) acc[i][jj] = MFMA_BF16(a[i], b[jj], acc[i][jj]);
    }

    // Two half-passes: half h covers fragment rows ii = h*2 + {0,1} of every
    // wave, i.e. global rows mblk*128 + wr*64 + h*32 + (0..31).
#pragma unroll
    for (int h = 0; h < 2; h++) {
        if (h) __syncthreads();          // drain(h=0) done before overwrite
#pragma unroll
        for (int i = 0; i < 2; i++) {
            const int ii = h * 2 + i;
            const int lrow = wr * 32 + i * 16 + q * 4;   // LDS row (0..63)
#pragma unroll
            for (int jj = 0; jj < 4; jj++) {
                const int col = wc * 64 + jj * 16 + l16;
#pragma unroll
                for (int r = 0; r < 4; r++) {
                    const float x = acc[ii][jj][r];
                    S[(lrow + r) * 132 + col] = 1.0f / (1.0f + __expf(-x));
                }
            }
        }
        __syncthreads();
        // drain 64 rows x 128 cols = 2048 dwordx4, fully coalesced
#pragma unroll
        for (int it = 0; it < 8; it++) {
            const int gid = it * 256 + (int)threadIdx.x;
            const int lr = gid >> 5;             // 0..63
            const int qd = gid & 31;             // 16B quad
            f32x4_t v = *(const f32x4_t*)(S + lr * 132 + qd * 4);
            const int grow = mblk * 128 + (lr >> 5) * 64 + (lr & 31) + h * 32;
            const int gcol = nblk * 128 + qd * 4;
            nt_store4(v, out + (size_t)grow * 8192 + gcol);
        }
    }
}

extern "C" void kernel_launch(void* const* d_in, const int* in_sizes, int n_in,
                              void* d_out, int out_size, void* d_ws, size_t ws_size,
                              hipStream_t stream)
{
    const float* adj  = (const float*)d_in[0];
    const float* feat = (const float*)d_in[1];
    const float* W1   = (const float*)d_in[2];
    const float* b1   = (const float*)d_in[3];
    const float* W2   = (const float*)d_in[4];
    const float* b2   = (const float*)d_in[5];
    float* out = (float*)d_out;

    // workspace layout (~36.3 MB used)
    char* p = (char*)d_ws;
    __bf16* featbf = (__bf16*)p; p += (size_t)8192 * 512 * 2;  // 8 MB
    __bf16* W1T    = (__bf16*)p; p += (size_t)256 * 512 * 2;   // 256 KB
    __bf16* W2T    = (__bf16*)p; p += (size_t)128 * 256 * 2;   // 64 KB
    __bf16* t1T    = (__bf16*)p; p += (size_t)256 * 8192 * 2;  // 4 MB
    __bf16* h1     = (__bf16*)p; p += (size_t)8192 * 256 * 2;  // 4 MB
    __bf16* t2T    = (__bf16*)p; p += (size_t)128 * 8192 * 2;  // 2 MB
    __bf16* hbf    = (__bf16*)p; p += (size_t)8192 * 128 * 2;  // 2 MB
    float* part    = (float*)p;                                 // 16 MB (split-K=2)

    // 1. casts
    cast_all<<<2688, 256, 0, stream>>>(feat, W1, W2, featbf, W1T, W2T);
    // 2. t1T[256][8192] = W1T * feat^T
    gemm_bt_cbf16<2, 2><<<dim3(4, 64), 256, 0, stream>>>(W1T, featbf, t1T, 512, 8192);
    // 3. partials of adj @ t1  (split-K=2, XCD-locked ks, 512-thread blocks)
    gemm_adj_lds<256><<<256, 512, 0, stream>>>(adj, t1T, part);
    // 4. h1 = relu(sum + b1) -> bf16
    epi_relu_bias<<<2048, 256, 0, stream>>>(part, b1, h1);
    // 5. t2T[128][8192] = W2T * h1^T
    gemm_bt_cbf16<2, 2><<<dim3(2, 64), 256, 0, stream>>>(W2T, h1, t2T, 256, 8192);
    // 6. partials of adj @ t2  (split-K=2, XCD-locked ks, 512-thread blocks)
    gemm_adj_lds<128><<<256, 512, 0, stream>>>(adj, t2T, part);
    // 7. h = sum + b2 -> fp32 out tail + bf16 copy
    epi_bias_out<<<1024, 256, 0, stream>>>(part, b2, out + (size_t)8192 * 8192, hbf);
    // 8. out = sigmoid(h @ h^T)
    gemm_sig<<<dim3(64, 64), 256, 0, stream>>>(hbf, out);
}